// Round 4
// baseline (1455.906 us; speedup 1.0000x reference)
//
#include <hip/hip_runtime.h>
#include <hip/hip_bf16.h>

// TGCN graph convolution: out = (L @ [inputs|hidden]) @ W + b
// N=16384, B=2, F=32, G=16, OUT=16.  L is ~1% sparse with exact zeros.
// Round 4: decouple streaming from gathering.
//   Pass 1 (compress_l): stream L at HBM rate, ballot-compact (k,val) per row.
//   Pass 2 (spmm_gather): consume lists; constant-lane shfl -> scalar
//     broadcast; 16 independent L2 gathers of xpb[k][48] in flight.
// Workspace: xpb 3MB @0, crow 6MB @4MB, lists 64MB @16MB, counts @96MB.

#define NN   16384
#define FF   32
#define GG   16
#define OUTD 16
#define C96  96
#define NSTRIDE 512   // list slots per row (max nz/row ~240 stat-bound)

__device__ __forceinline__ unsigned int pack_bf2(float lo, float hi) {
  unsigned short a = __builtin_bit_cast(unsigned short, __float2bfloat16(lo));
  unsigned short b = __builtin_bit_cast(unsigned short, __float2bfloat16(hi));
  return (unsigned int)a | ((unsigned int)b << 16);
}

// ---------------------------------------------------------------------------
// Prep: xpb[k][48] uint; pair c2 holds bf16(cat[k][2c2]),bf16(cat[k][2c2+1]).
// cat cols: [0:32)=inp[0][k], [32:48)=hid[0][k], [48:80)=inp[1][k],
// [80:96)=hid[1][k].
// ---------------------------------------------------------------------------
__global__ __launch_bounds__(256) void prep_xp(const float* __restrict__ inp,
                                               const float* __restrict__ hid,
                                               unsigned int* __restrict__ xpb) {
  int gid = blockIdx.x * 256 + threadIdx.x;   // 16384*12 units
  int k = gid / 12;
  int j = gid - k * 12;
  const float* src;
  if (j < 4)       src = inp + (size_t)k * FF + 8 * j;
  else if (j < 6)  src = hid + (size_t)k * GG + 8 * (j - 4);
  else if (j < 10) src = inp + ((size_t)NN + k) * FF + 8 * (j - 6);
  else             src = hid + ((size_t)NN + k) * GG + 8 * (j - 10);
  float4 v0 = *(const float4*)src;
  float4 v1 = *(const float4*)(src + 4);
  uint4 o;
  o.x = pack_bf2(v0.x, v0.y);
  o.y = pack_bf2(v0.z, v0.w);
  o.z = pack_bf2(v1.x, v1.y);
  o.w = pack_bf2(v1.z, v1.w);
  ((uint4*)xpb)[gid] = o;
}

// ---------------------------------------------------------------------------
// Pass 1: stream L, compact nonzeros. Wave per row, 4 chunks (4 KB) per
// group, 16 ballots/group. Position = cnt + popc(mask & below-lane).
// Pad list to multiple of 64 with (k=0,val=0) so pass 2 is branchless.
// ---------------------------------------------------------------------------
__global__ __launch_bounds__(256) void compress_l(const float* __restrict__ L,
                                                  uint2* __restrict__ lists,
                                                  unsigned int* __restrict__ counts) {
  const int lane = threadIdx.x & 63;
  const int wave = threadIdx.x >> 6;
  const int m = blockIdx.x * 4 + wave;
  const float4* lrow4 = (const float4*)(L + (size_t)m * NN);
  uint2* rowlist = lists + (size_t)m * NSTRIDE;
  const unsigned long long below = (1ull << lane) - 1ull;
  unsigned int cnt = 0;

  for (int g = 0; g < 16; ++g) {
    float4 v[4];
#pragma unroll
    for (int c = 0; c < 4; ++c) v[c] = lrow4[(g * 4 + c) * 64 + lane];
#pragma unroll
    for (int c = 0; c < 4; ++c) {
      const int kb = (g * 4 + c) * 256 + lane * 4;
#pragma unroll
      for (int e = 0; e < 4; ++e) {
        float x = (e == 0) ? v[c].x : (e == 1) ? v[c].y : (e == 2) ? v[c].z : v[c].w;
        unsigned long long msk = __ballot(x != 0.0f);
        if (x != 0.0f) {
          unsigned int pos = cnt + (unsigned)__popcll(msk & below);
          rowlist[pos] = make_uint2((unsigned)(kb + e),
                                    __builtin_bit_cast(unsigned int, x));
        }
        cnt += (unsigned)__popcll(msk);
      }
    }
  }
  unsigned int pad = (64u - (cnt & 63u)) & 63u;
  if ((unsigned)lane < pad) rowlist[cnt + lane] = make_uint2(0u, 0u);
  cnt += pad;
  if (lane == 0) counts[m] = cnt;
}

// ---------------------------------------------------------------------------
// Pass 2: wave per row. Batch of 64 entries = one coalesced 512B load;
// inner loop: constant-lane shfl (readlane/scalar broadcast) + L2 gather of
// xpb[k][cl] + 2 fmacs. Lane cl<48 owns cols {2cl,2cl+1}.
// ---------------------------------------------------------------------------
__global__ __launch_bounds__(256) void spmm_gather(const uint2* __restrict__ lists,
                                                   const unsigned int* __restrict__ counts,
                                                   const unsigned int* __restrict__ xpb,
                                                   float* __restrict__ crow) {
  const int lane = threadIdx.x & 63;
  const int wave = threadIdx.x >> 6;
  const int m = blockIdx.x * 4 + wave;
  const int cl = lane < 48 ? lane : lane - 48;
  const uint2* rowlist = lists + (size_t)m * NSTRIDE;
  const unsigned int cnt = counts[m];   // same-address broadcast load
  float accx = 0.f, accy = 0.f;

  for (unsigned int b = 0; b < cnt; b += 64) {
    uint2 kv = rowlist[b + lane];
#pragma unroll 16
    for (int j = 0; j < 64; ++j) {
      unsigned int k = (unsigned int)__shfl((int)kv.x, j);
      float val = __builtin_bit_cast(float, (unsigned int)__shfl((int)kv.y, j));
      unsigned int u = xpb[(size_t)k * 48 + cl];
      accx += val * __builtin_bit_cast(float, u << 16);
      accy += val * __builtin_bit_cast(float, u & 0xffff0000u);
    }
  }

  if (lane < 48) {
    float2 o = {accx, accy};
    *(float2*)(crow + (size_t)m * C96 + 2 * lane) = o;
  }
}

// ---------------------------------------------------------------------------
// Epilogue: out[b][n][:16] = crow[n][b*48:(b+1)*48] @ W + bias.
// ---------------------------------------------------------------------------
__global__ __launch_bounds__(256) void epilogue(const float* __restrict__ cp,
                                                const float* __restrict__ w,
                                                const float* __restrict__ bias,
                                                float* __restrict__ out) {
  __shared__ float lds_c[64 * 97];
  __shared__ float lds_w[48 * 16];
  __shared__ float lds_bias[16];
  const int tid = threadIdx.x;
  const int n0 = blockIdx.x * 64;

  for (int i = tid; i < 768; i += 256) lds_w[i] = w[i];
  if (tid < 16) lds_bias[tid] = bias[tid];

  const size_t base = (size_t)n0 * C96;
#pragma unroll
  for (int i = 0; i < 24; ++i) {
    int e = tid + i * 256;   // 0..6143 over [64 x 96]
    lds_c[e + e / 96] = cp[base + e];
  }
  __syncthreads();

  const int node = tid >> 2;
  const int b = (tid >> 1) & 1;
  const int o0 = (tid & 1) * 8;
  const float* crow_l = &lds_c[node * 97 + b * 48];
  float accv[8];
#pragma unroll
  for (int o = 0; o < 8; ++o) accv[o] = lds_bias[o0 + o];
#pragma unroll
  for (int j = 0; j < 48; ++j) {
    float cv = crow_l[j];
#pragma unroll
    for (int o = 0; o < 8; ++o) accv[o] += cv * lds_w[j * 16 + o0 + o];
  }
  size_t ob = (size_t)b * ((size_t)NN * OUTD) + (size_t)(n0 + node) * OUTD + o0;
  float4 v0 = {accv[0], accv[1], accv[2], accv[3]};
  float4 v1 = {accv[4], accv[5], accv[6], accv[7]};
  *(float4*)(out + ob) = v0;
  *(float4*)(out + ob + 4) = v1;
}

extern "C" void kernel_launch(void* const* d_in, const int* in_sizes, int n_in,
                              void* d_out, int out_size, void* d_ws, size_t ws_size,
                              hipStream_t stream) {
  (void)in_sizes; (void)n_in; (void)out_size; (void)ws_size;
  const float* inp = (const float*)d_in[0];   // [2,16384,32]
  const float* hid = (const float*)d_in[1];   // [2,16384*16]
  const float* lap = (const float*)d_in[2];   // [16384,16384]
  const float* wts = (const float*)d_in[3];   // [48,16]
  const float* bia = (const float*)d_in[4];   // [16]
  float* out = (float*)d_out;                 // [2,16384*16]

  unsigned int* xpb = (unsigned int*)d_ws;                        // 3 MB
  float* crow = (float*)((char*)d_ws + (4u << 20));               // 6 MB
  uint2* lists = (uint2*)((char*)d_ws + (16u << 20));             // 64 MB
  unsigned int* counts = (unsigned int*)((char*)d_ws + (96u << 20));

  prep_xp<<<(NN * 12) / 256, 256, 0, stream>>>(inp, hid, xpb);
  compress_l<<<NN / 4, 256, 0, stream>>>(lap, lists, counts);
  spmm_gather<<<NN / 4, 256, 0, stream>>>(lists, counts, xpb, crow);
  epilogue<<<NN / 64, 256, 0, stream>>>(crow, wts, bia, out);
}

// Round 5
// 1411.134 us; speedup vs baseline: 1.0317x; 1.0317x over previous
//
#include <hip/hip_runtime.h>
#include <hip/hip_bf16.h>

// TGCN graph convolution: out = (L @ [inputs|hidden]) @ W + b
// N=16384, B=2, F=32, G=16, OUT=16.  Dominant cost: stream L (1.07 GB fp32).
// Round 5: r1 structure with BK=128 (4x bigger K-tile per barrier drain),
// A (32KB fp32) + B (24KB bf16) both LDS-staged via global_load_lds(16B),
// XOR-swizzled slots baked into global src addresses (2-way bank-free reads).
// 2 blocks/CU (56 KB LDS each), SPLITK=2 XCD-aligned so xt stays L2-resident.
// Workspace: xt bf16 3 MB @ ws+0, cp fp32 partials 12.6 MB @ ws+4MB.

#define NN   16384
#define FF   32
#define GG   16
#define OUTD 16
#define C96  96
#define BM   64
#define BK   128
#define SPLITK 2
#define KCHUNK (NN / SPLITK)      // 8192
#define KITERS (KCHUNK / BK)      // 64

typedef __attribute__((ext_vector_type(8))) short short8;
typedef __attribute__((ext_vector_type(4))) float f32x4;

using as1_void = __attribute__((address_space(1))) void;
using as3_void = __attribute__((address_space(3))) void;

__device__ __forceinline__ unsigned short f2bf(float f) {
  __hip_bfloat16 h = __float2bfloat16(f);
  return __builtin_bit_cast(unsigned short, h);
}

// ---------------------------------------------------------------------------
// Prep: Xt[c][n] bf16, c = b*48 + (f | 32+g), via LDS transpose (coalesced).
// ---------------------------------------------------------------------------
__global__ __launch_bounds__(256) void prep_xt(const float* __restrict__ inp,
                                               const float* __restrict__ hid,
                                               unsigned short* __restrict__ xt) {
  __shared__ float lds_cat[C96][64];
  const int tid = threadIdx.x;
  const int n0 = blockIdx.x * 64;

#pragma unroll
  for (int r = 0; r < 2; ++r) {
    int fi = tid + r * 256;       // 0..511
    int n = fi >> 3;
    int f4 = fi & 7;
#pragma unroll
    for (int b = 0; b < 2; ++b) {
      const float4* src = (const float4*)(inp + ((size_t)b * NN + (n0 + n)) * FF) + f4;
      float4 v = *src;
      int c = b * 48 + f4 * 4;
      lds_cat[c + 0][n] = v.x;
      lds_cat[c + 1][n] = v.y;
      lds_cat[c + 2][n] = v.z;
      lds_cat[c + 3][n] = v.w;
    }
  }
  {
    int n = tid >> 2;
    int g4 = tid & 3;
#pragma unroll
    for (int b = 0; b < 2; ++b) {
      const float4* src = (const float4*)(hid + ((size_t)b * NN + (n0 + n)) * GG) + g4;
      float4 v = *src;
      int c = b * 48 + 32 + g4 * 4;
      lds_cat[c + 0][n] = v.x;
      lds_cat[c + 1][n] = v.y;
      lds_cat[c + 2][n] = v.z;
      lds_cat[c + 3][n] = v.w;
    }
  }
  __syncthreads();
#pragma unroll
  for (int r = 0; r < 3; ++r) {
    int u = tid + r * 256;
    int c = u >> 3;
    int nn = (u & 7) * 8;
    short8 o;
#pragma unroll
    for (int j = 0; j < 8; ++j) o[j] = (short)f2bf(lds_cat[c][nn + j]);
    *(short8*)(xt + (size_t)c * NN + n0 + nn) = o;
  }
}

// ---------------------------------------------------------------------------
// Main: Cp[sp][m][c] partial over k in [sp*8192,(sp+1)*8192), BK=128 tiles.
// A LDS: 64 rows x 32 units(16B); unit c of row stored at slot row*32+(c^(row&7)).
// B LDS: 96 cols x 16 units(16B); unit u of col stored at slot col*16+(u^(col&7)).
// Fill: 32 A-loads (2 rows x 32 lanes each) + 24 B-loads (4 cols x 16 lanes),
// swizzle applied to global src (permutes within a 512B/256B segment: still
// fully coalesced).  Wave w computes rows [16w,16w+16) x 96 cols: per k-step
// 2 A ds_read_b128 + 6 B ds_read_b128 + 6 MFMA.  All frag reads 2-way = free.
// ---------------------------------------------------------------------------
__global__ __launch_bounds__(256, 2) void spmm_main(const float* __restrict__ L,
                                                    const unsigned short* __restrict__ xt,
                                                    float* __restrict__ cp) {
  __shared__ __align__(16) float lds_a[BM * BK];            // 32 KB
  __shared__ __align__(16) unsigned short lds_b[C96 * BK];  // 24 KB

  const int tid = threadIdx.x;
  const int wave = tid >> 6;
  const int lane = tid & 63;
  const int m = lane & 15;
  const int quad = lane >> 4;
  const int sp = blockIdx.x & 1;            // XCD x -> sp = x&1 (L2-resident xt)
  const int m0 = (blockIdx.x >> 1) * BM;
  const int kb = sp * KCHUNK;

  // ---- staging descriptors (iteration-invariant) ----
  // A: 8 load-instrs per wave, instr l covers rows 2l..2l+1 (l = wave*8+i)
  const float* asrc[8];
  float* adst[8];
#pragma unroll
  for (int i = 0; i < 8; ++i) {
    int l = wave * 8 + i;
    int row = 2 * l + (lane >> 5);
    int cu = (lane & 31) ^ (row & 7);
    asrc[i] = L + (size_t)(m0 + row) * NN + kb + cu * 4;
    adst[i] = lds_a + l * 256;              // wave-uniform (l*64 units *4 fl)
  }
  // B: 6 load-instrs per wave, instr l covers cols 4l..4l+3
  const unsigned short* bsrc[6];
  unsigned short* bdst[6];
#pragma unroll
  for (int i = 0; i < 6; ++i) {
    int l = wave * 6 + i;
    int col = 4 * l + (lane >> 4);
    int cb = (lane & 15) ^ (col & 7);
    bsrc[i] = xt + (size_t)col * NN + kb + cb * 8;
    bdst[i] = lds_b + l * 512;              // wave-uniform (l*64 units *8 bf16)
  }

  // ---- fragment LDS offsets ----
  const int rowA = wave * 16 + m;
  int aoff[4][2];
#pragma unroll
  for (int kk = 0; kk < 4; ++kk) {
    int c0 = kk * 8 + quad * 2;
    aoff[kk][0] = (rowA * 32 + (c0 ^ (rowA & 7))) * 4;
    aoff[kk][1] = (rowA * 32 + ((c0 + 1) ^ (rowA & 7))) * 4;
  }
  int boff[4][6];
#pragma unroll
  for (int kk = 0; kk < 4; ++kk)
#pragma unroll
    for (int t = 0; t < 6; ++t) {
      int col = t * 16 + m;
      int u = kk * 4 + quad;
      boff[kk][t] = (col * 16 + (u ^ (col & 7))) * 8;
    }

  f32x4 acc[6];
#pragma unroll
  for (int t = 0; t < 6; ++t) acc[t] = (f32x4){0.f, 0.f, 0.f, 0.f};

  for (int it = 0; it < KITERS; ++it) {
    const int ko = it * BK;
#pragma unroll
    for (int i = 0; i < 8; ++i)
      __builtin_amdgcn_global_load_lds((const as1_void*)(asrc[i] + ko),
                                       (as3_void*)adst[i], 16, 0, 0);
#pragma unroll
    for (int i = 0; i < 6; ++i)
      __builtin_amdgcn_global_load_lds((const as1_void*)(bsrc[i] + ko),
                                       (as3_void*)bdst[i], 16, 0, 0);
    __syncthreads();

#pragma unroll
    for (int kk = 0; kk < 4; ++kk) {
      f32x4 a0 = *(const f32x4*)(lds_a + aoff[kk][0]);
      f32x4 a1 = *(const f32x4*)(lds_a + aoff[kk][1]);
      short8 af;
      af[0] = (short)f2bf(a0[0]); af[1] = (short)f2bf(a0[1]);
      af[2] = (short)f2bf(a0[2]); af[3] = (short)f2bf(a0[3]);
      af[4] = (short)f2bf(a1[0]); af[5] = (short)f2bf(a1[1]);
      af[6] = (short)f2bf(a1[2]); af[7] = (short)f2bf(a1[3]);
#pragma unroll
      for (int t = 0; t < 6; ++t) {
        short8 bf = *(const short8*)(lds_b + boff[kk][t]);
        acc[t] = __builtin_amdgcn_mfma_f32_16x16x32_bf16(af, bf, acc[t], 0, 0, 0);
      }
    }
    __syncthreads();
  }

  // store split-K partial: C/D layout col=lane&15, row=quad*4+reg
  float* cpd = cp + ((size_t)sp * NN + m0) * C96;
#pragma unroll
  for (int t = 0; t < 6; ++t) {
    int col = t * 16 + m;
#pragma unroll
    for (int r = 0; r < 4; ++r) {
      int row = wave * 16 + quad * 4 + r;
      cpd[(size_t)row * C96 + col] = acc[t][r];
    }
  }
}

// ---------------------------------------------------------------------------
// Epilogue: sum split-K partials, apply W[48x16] + bias, write out[2][N][16].
// ---------------------------------------------------------------------------
__global__ __launch_bounds__(256) void epilogue(const float* __restrict__ cp,
                                                const float* __restrict__ w,
                                                const float* __restrict__ bias,
                                                float* __restrict__ out) {
  __shared__ float lds_c[64 * 97];
  __shared__ float lds_w[48 * 16];
  __shared__ float lds_bias[16];
  const int tid = threadIdx.x;
  const int n0 = blockIdx.x * 64;

  for (int i = tid; i < 768; i += 256) lds_w[i] = w[i];
  if (tid < 16) lds_bias[tid] = bias[tid];

  const size_t base = (size_t)n0 * C96;
#pragma unroll
  for (int i = 0; i < 24; ++i) {
    int e = tid + i * 256;   // 0..6143 over [64 x 96]
    float s = 0.f;
#pragma unroll
    for (int sp = 0; sp < SPLITK; ++sp)
      s += cp[(size_t)sp * ((size_t)NN * C96) + base + e];
    lds_c[e + e / 96] = s;
  }
  __syncthreads();

  const int node = tid >> 2;
  const int b = (tid >> 1) & 1;
  const int o0 = (tid & 1) * 8;
  const float* crow_l = &lds_c[node * 97 + b * 48];
  float accv[8];
#pragma unroll
  for (int o = 0; o < 8; ++o) accv[o] = lds_bias[o0 + o];
#pragma unroll
  for (int j = 0; j < 48; ++j) {
    float cv = crow_l[j];
#pragma unroll
    for (int o = 0; o < 8; ++o) accv[o] += cv * lds_w[j * 16 + o0 + o];
  }
  size_t ob = (size_t)b * ((size_t)NN * OUTD) + (size_t)(n0 + node) * OUTD + o0;
  float4 v0 = {accv[0], accv[1], accv[2], accv[3]};
  float4 v1 = {accv[4], accv[5], accv[6], accv[7]};
  *(float4*)(out + ob) = v0;
  *(float4*)(out + ob + 4) = v1;
}

extern "C" void kernel_launch(void* const* d_in, const int* in_sizes, int n_in,
                              void* d_out, int out_size, void* d_ws, size_t ws_size,
                              hipStream_t stream) {
  (void)in_sizes; (void)n_in; (void)out_size; (void)ws_size;
  const float* inp = (const float*)d_in[0];   // [2,16384,32]
  const float* hid = (const float*)d_in[1];   // [2,16384*16]
  const float* lap = (const float*)d_in[2];   // [16384,16384]
  const float* wts = (const float*)d_in[3];   // [48,16]
  const float* bia = (const float*)d_in[4];   // [16]
  float* out = (float*)d_out;                 // [2,16384*16]

  unsigned short* xt = (unsigned short*)d_ws;             // 3 MB bf16
  float* cp = (float*)((char*)d_ws + (4u << 20));         // 12.6 MB fp32

  prep_xt<<<NN / 64, 256, 0, stream>>>(inp, hid, xt);
  spmm_main<<<(NN / BM) * SPLITK, 256, 0, stream>>>(lap, xt, cp);
  epilogue<<<NN / 64, 256, 0, stream>>>(cp, wts, bia, out);
}

// Round 6
// 1392.582 us; speedup vs baseline: 1.0455x; 1.0133x over previous
//
#include <hip/hip_runtime.h>
#include <hip/hip_bf16.h>

// TGCN graph convolution: out = (L @ [inputs|hidden]) @ W + b
// N=16384, B=2, F=32, G=16, OUT=16.  Dominant cost: stream L (1.07 GB fp32).
// Round 6: double-buffered LDS with ONE barrier per iter:
//   barrier -> issue loads into buf[p^1] -> compute buf[p].
// Loads stay in flight across the whole compute phase (continuous HBM
// stream), unlike the 2-barrier r1 structure where loads only fly during the
// drain. BK=32 (small latency quantum), BM=64, SPLITK=4, 28 KB LDS,
// 4 blocks/CU. Bank-conflict-free ds_read_b128 layouts for A and B.
// Workspace: xt bf16 3 MB @ ws+0, cp fp32 partials 25 MB @ ws+4MB.

#define NN   16384
#define FF   32
#define GG   16
#define OUTD 16
#define C96  96
#define BM   64
#define BK   32
#define SPLITK 4
#define KCHUNK (NN / SPLITK)      // 4096
#define KITERS (KCHUNK / BK)      // 128

typedef __attribute__((ext_vector_type(8))) short short8;
typedef __attribute__((ext_vector_type(4))) float f32x4;

using as1_void = __attribute__((address_space(1))) void;
using as3_void = __attribute__((address_space(3))) void;

__device__ __forceinline__ unsigned short f2bf(float f) {
  __hip_bfloat16 h = __float2bfloat16(f);
  return __builtin_bit_cast(unsigned short, h);
}

// ---------------------------------------------------------------------------
// Prep: Xt[c][n] bf16, c = b*48 + (f | 32+g), via LDS transpose (coalesced).
// ---------------------------------------------------------------------------
__global__ __launch_bounds__(256) void prep_xt(const float* __restrict__ inp,
                                               const float* __restrict__ hid,
                                               unsigned short* __restrict__ xt) {
  __shared__ float lds_cat[C96][64];
  const int tid = threadIdx.x;
  const int n0 = blockIdx.x * 64;

#pragma unroll
  for (int r = 0; r < 2; ++r) {
    int fi = tid + r * 256;       // 0..511
    int n = fi >> 3;
    int f4 = fi & 7;
#pragma unroll
    for (int b = 0; b < 2; ++b) {
      const float4* src = (const float4*)(inp + ((size_t)b * NN + (n0 + n)) * FF) + f4;
      float4 v = *src;
      int c = b * 48 + f4 * 4;
      lds_cat[c + 0][n] = v.x;
      lds_cat[c + 1][n] = v.y;
      lds_cat[c + 2][n] = v.z;
      lds_cat[c + 3][n] = v.w;
    }
  }
  {
    int n = tid >> 2;
    int g4 = tid & 3;
#pragma unroll
    for (int b = 0; b < 2; ++b) {
      const float4* src = (const float4*)(hid + ((size_t)b * NN + (n0 + n)) * GG) + g4;
      float4 v = *src;
      int c = b * 48 + 32 + g4 * 4;
      lds_cat[c + 0][n] = v.x;
      lds_cat[c + 1][n] = v.y;
      lds_cat[c + 2][n] = v.z;
      lds_cat[c + 3][n] = v.w;
    }
  }
  __syncthreads();
#pragma unroll
  for (int r = 0; r < 3; ++r) {
    int u = tid + r * 256;
    int c = u >> 3;
    int nn = (u & 7) * 8;
    short8 o;
#pragma unroll
    for (int j = 0; j < 8; ++j) o[j] = (short)f2bf(lds_cat[c][nn + j]);
    *(short8*)(xt + (size_t)c * NN + n0 + nn) = o;
  }
}

// ---------------------------------------------------------------------------
// Main GEMM.  A LDS layout: slot(row,cu) = row*8 + (cu ^ (row&7)), 16B units
// (frag reads: 8-lane subgroups hit 8 distinct bank groups -> conflict-free;
// global fill: 128B per row, lane-permuted within the segment -> coalesced).
// B LDS layout: slot = t*64 + u*16 + c  (t=col/16, c=col%16, u=k-unit 0..3);
// frag reads consecutive slots -> conflict-free; fill reads 16 rows x 64B
// from L2-resident xt.
// Loop: __syncthreads(); issue next tile into buf[p^1]; compute buf[p].
// ---------------------------------------------------------------------------
__global__ __launch_bounds__(256, 4) void spmm_main(const float* __restrict__ L,
                                                    const unsigned short* __restrict__ xt,
                                                    float* __restrict__ cp) {
  __shared__ __align__(16) float lds_a[2][BM * 8 * 4];         // 2 x 8 KB
  __shared__ __align__(16) unsigned short lds_b[2][C96 * BK];  // 2 x 6 KB

  const int tid = threadIdx.x;
  const int wave = tid >> 6;
  const int lane = tid & 63;
  const int m = lane & 15;
  const int quad = lane >> 4;
  const int bx = blockIdx.x;
  const int sp = bx & 3;               // bx%8 = XCD -> one sp per XCD
  const int m0 = (bx >> 2) * BM;
  const int kb = sp * KCHUNK;

  // ---- A staging: 8 instrs/block, 2 per wave ----
  const float* asrc[2];
  float* adst0[2], *adst1[2];
#pragma unroll
  for (int i = 0; i < 2; ++i) {
    int l = wave * 2 + i;
    int s = l * 64 + lane;
    int row = s >> 3;
    int cu = (s & 7) ^ (row & 7);
    asrc[i] = L + (size_t)(m0 + row) * NN + kb + cu * 4;
    adst0[i] = &lds_a[0][l * 256];
    adst1[i] = &lds_a[1][l * 256];
  }
  // ---- B staging: 6 instrs/block, waves 0-2 take 2 each ----
  const unsigned short* bsrc[2];
  unsigned short* bdst0[2], *bdst1[2];
  const bool has_b = (wave < 3);
  if (has_b) {
#pragma unroll
    for (int i = 0; i < 2; ++i) {
      int t = wave * 2 + i;
      int col = t * 16 + m;
      int u = quad;
      bsrc[i] = xt + (size_t)col * NN + kb + u * 8;
      bdst0[i] = &lds_b[0][t * 512];
      bdst1[i] = &lds_b[1][t * 512];
    }
  }

  // ---- fragment LDS offsets ----
  const int rowA = wave * 16 + m;
  const int aoff0 = (rowA * 8 + ((quad * 2) ^ (rowA & 7))) * 4;      // floats
  const int aoff1 = (rowA * 8 + ((quad * 2 + 1) ^ (rowA & 7))) * 4;
  int boff[6];
#pragma unroll
  for (int t = 0; t < 6; ++t)
    boff[t] = (t * 64 + quad * 16 + m) * 8;                          // shorts

  f32x4 acc[6];
#pragma unroll
  for (int t = 0; t < 6; ++t) acc[t] = (f32x4){0.f, 0.f, 0.f, 0.f};

  // ---- prologue: issue tile 0 into buf 0 ----
#pragma unroll
  for (int i = 0; i < 2; ++i)
    __builtin_amdgcn_global_load_lds((const as1_void*)asrc[i],
                                     (as3_void*)adst0[i], 16, 0, 0);
  if (has_b) {
#pragma unroll
    for (int i = 0; i < 2; ++i)
      __builtin_amdgcn_global_load_lds((const as1_void*)bsrc[i],
                                       (as3_void*)bdst0[i], 16, 0, 0);
  }

  for (int it = 0; it < KITERS; ++it) {
    __syncthreads();   // drains buf[it&1] loads (in flight for a full iter)

    if (it + 1 < KITERS) {
      const int ko = (it + 1) * BK;
      if ((it & 1) == 0) {
#pragma unroll
        for (int i = 0; i < 2; ++i)
          __builtin_amdgcn_global_load_lds((const as1_void*)(asrc[i] + ko),
                                           (as3_void*)adst1[i], 16, 0, 0);
        if (has_b)
#pragma unroll
          for (int i = 0; i < 2; ++i)
            __builtin_amdgcn_global_load_lds((const as1_void*)(bsrc[i] + ko),
                                             (as3_void*)bdst1[i], 16, 0, 0);
      } else {
#pragma unroll
        for (int i = 0; i < 2; ++i)
          __builtin_amdgcn_global_load_lds((const as1_void*)(asrc[i] + ko),
                                           (as3_void*)adst0[i], 16, 0, 0);
        if (has_b)
#pragma unroll
          for (int i = 0; i < 2; ++i)
            __builtin_amdgcn_global_load_lds((const as1_void*)(bsrc[i] + ko),
                                             (as3_void*)bdst0[i], 16, 0, 0);
      }
    }

    // ---- compute from buf[it&1] ----
    const float* ab = lds_a[it & 1];
    const unsigned short* bb = lds_b[it & 1];
    f32x4 a0 = *(const f32x4*)(ab + aoff0);
    f32x4 a1 = *(const f32x4*)(ab + aoff1);
    short8 af;
    af[0] = (short)f2bf(a0[0]); af[1] = (short)f2bf(a0[1]);
    af[2] = (short)f2bf(a0[2]); af[3] = (short)f2bf(a0[3]);
    af[4] = (short)f2bf(a1[0]); af[5] = (short)f2bf(a1[1]);
    af[6] = (short)f2bf(a1[2]); af[7] = (short)f2bf(a1[3]);
#pragma unroll
    for (int t = 0; t < 6; ++t) {
      short8 bf = *(const short8*)(bb + boff[t]);
      acc[t] = __builtin_amdgcn_mfma_f32_16x16x32_bf16(af, bf, acc[t], 0, 0, 0);
    }
  }

  // store split-K partial: C/D layout col=lane&15, row=quad*4+reg
  float* cpd = cp + ((size_t)sp * NN + m0) * C96;
#pragma unroll
  for (int t = 0; t < 6; ++t) {
    int col = t * 16 + m;
#pragma unroll
    for (int r = 0; r < 4; ++r) {
      int row = wave * 16 + quad * 4 + r;
      cpd[(size_t)row * C96 + col] = acc[t][r];
    }
  }
}

// ---------------------------------------------------------------------------
// Epilogue: sum split-K partials, apply W[48x16] + bias, write out[2][N][16].
// ---------------------------------------------------------------------------
__global__ __launch_bounds__(256) void epilogue(const float* __restrict__ cp,
                                                const float* __restrict__ w,
                                                const float* __restrict__ bias,
                                                float* __restrict__ out) {
  __shared__ float lds_c[64 * 97];
  __shared__ float lds_w[48 * 16];
  __shared__ float lds_bias[16];
  const int tid = threadIdx.x;
  const int n0 = blockIdx.x * 64;

  for (int i = tid; i < 768; i += 256) lds_w[i] = w[i];
  if (tid < 16) lds_bias[tid] = bias[tid];

  const size_t base = (size_t)n0 * C96;
#pragma unroll
  for (int i = 0; i < 24; ++i) {
    int e = tid + i * 256;   // 0..6143 over [64 x 96]
    float s = 0.f;
#pragma unroll
    for (int sp = 0; sp < SPLITK; ++sp)
      s += cp[(size_t)sp * ((size_t)NN * C96) + base + e];
    lds_c[e + e / 96] = s;
  }
  __syncthreads();

  const int node = tid >> 2;
  const int b = (tid >> 1) & 1;
  const int o0 = (tid & 1) * 8;
  const float* crow_l = &lds_c[node * 97 + b * 48];
  float accv[8];
#pragma unroll
  for (int o = 0; o < 8; ++o) accv[o] = lds_bias[o0 + o];
#pragma unroll
  for (int j = 0; j < 48; ++j) {
    float cv = crow_l[j];
#pragma unroll
    for (int o = 0; o < 8; ++o) accv[o] += cv * lds_w[j * 16 + o0 + o];
  }
  size_t ob = (size_t)b * ((size_t)NN * OUTD) + (size_t)(n0 + node) * OUTD + o0;
  float4 v0 = {accv[0], accv[1], accv[2], accv[3]};
  float4 v1 = {accv[4], accv[5], accv[6], accv[7]};
  *(float4*)(out + ob) = v0;
  *(float4*)(out + ob + 4) = v1;
}

extern "C" void kernel_launch(void* const* d_in, const int* in_sizes, int n_in,
                              void* d_out, int out_size, void* d_ws, size_t ws_size,
                              hipStream_t stream) {
  (void)in_sizes; (void)n_in; (void)out_size; (void)ws_size;
  const float* inp = (const float*)d_in[0];   // [2,16384,32]
  const float* hid = (const float*)d_in[1];   // [2,16384*16]
  const float* lap = (const float*)d_in[2];   // [16384,16384]
  const float* wts = (const float*)d_in[3];   // [48,16]
  const float* bia = (const float*)d_in[4];   // [16]
  float* out = (float*)d_out;                 // [2,16384*16]

  unsigned short* xt = (unsigned short*)d_ws;             // 3 MB bf16
  float* cp = (float*)((char*)d_ws + (4u << 20));         // 25 MB fp32

  prep_xt<<<NN / 64, 256, 0, stream>>>(inp, hid, xt);
  spmm_main<<<(NN / BM) * SPLITK, 256, 0, stream>>>(lap, xt, cp);
  epilogue<<<NN / 64, 256, 0, stream>>>(cp, wts, bia, out);
}